// Round 6
// baseline (1440.503 us; speedup 1.0000x reference)
//
#include <hip/hip_runtime.h>

#define NN 25600      // nodes = 160*160
#define HH 160
#define WW 160
#define C2 256
#define GRID 800      // co-resident: launch_bounds(256,4) guarantees >=1024 capacity

// ---- bf16 weight pack offsets (ushorts) ----
#define B_WIN   0
#define B_WID   32768
#define B_WGAT  65536      // 2 layers x 65536
#define B_WOUT  196608
#define B_WEND  262144

// ---- small fp32 param offsets inside cvt (floats) ----
#define C_BNA   0          // 2x256 BN scale
#define C_BNB   512        // 2x256 BN shift (bias/mean folded)
#define C_ASRC  1024       // 2x256
#define C_ADST  1536       // 2x256
#define C_SEW1  2048       // 64x256
#define C_SEB1  18432      // 64
#define C_SEW2  18496      // 256x64
#define C_SEB2  34880      // 256
#define C_END   35136

typedef __attribute__((ext_vector_type(8))) short bfrag;   // 8 bf16 (4 VGPRs)
typedef __attribute__((ext_vector_type(4))) float ffrag;   // 4 fp32 acc

struct SmemG2 { unsigned short As[128*40], Bi[64*40], Bd[64*40]; }; // 20480 B
struct SmemG  { unsigned short As[128*40], Bs[64*40]; };            // 15360 B
struct SmemAg { float es[8][11][8]; float alpha[8][11][8]; };       // 5632 B
struct SmemTr { unsigned short T[64*136]; };                        // 17408 B
struct SmemFi { float T[64][65]; float mv[256]; float hv[64]; float sv[256]; }; // 18944 B
union  SmemAll { SmemG2 g2; SmemG g; SmemAg a; SmemTr t; SmemFi f; };

__device__ __forceinline__ float b2f(unsigned short u) {
    union { unsigned int ui; float f; } v; v.ui = ((unsigned int)u) << 16; return v.f;
}
__device__ __forceinline__ unsigned short f2b(float f) {
    union { float f; unsigned int u; } v; v.f = f;
    unsigned int u = v.u;
    unsigned int r = (u + 0x7FFFu + ((u >> 16) & 1u)) >> 16;
    return (unsigned short)r;
}
__device__ __forceinline__ float lo16f(unsigned int w) {
    union { unsigned int ui; float f; } v; v.ui = w << 16; return v.f;
}
__device__ __forceinline__ float hi16f(unsigned int w) {
    union { unsigned int ui; float f; } v; v.ui = w & 0xFFFF0000u; return v.f;
}
// Wave-uniform dtype probe on first 512 halfwords of x.
__device__ __forceinline__ bool probe_f32(const unsigned short* __restrict__ x) {
    int l = threadIdx.x & 63;
    bool wild = false;
#pragma unroll
    for (int i = 0; i < 8; ++i) {
        float v = b2f(x[l * 8 + i]);
        wild |= !(fabsf(v) < 1e6f);
    }
    return __any(wild);
}
__device__ __forceinline__ float ldf(const void* p, long i, bool f32) {
    return f32 ? ((const float*)p)[i] : b2f(((const unsigned short*)p)[i]);
}

// Grid barrier: monotonic-phase arrival counter (zeroed by host memset).
__device__ __forceinline__ void grid_bar(int* bar, int target) {
    __syncthreads();
    if (threadIdx.x == 0) {
        __threadfence();                                   // release all phase writes
        atomicAdd(bar, 1);
        while (__hip_atomic_load(bar, __ATOMIC_ACQUIRE, __HIP_MEMORY_SCOPE_AGENT) < target)
            __builtin_amdgcn_s_sleep(8);
    }
    __syncthreads();
}

__global__ __launch_bounds__(256, 4) void mega_kernel(
    const unsigned short* __restrict__ xp,   // x raw (probe + transpose src)
    const void* pwid, const void* pwin, const void* pwgat, const void* pwout,
    const void* pasrc, const void* padst, const void* pgbias,
    const void* pbng, const void* pbnb, const void* pbnm, const void* pbnv,
    const void* psew1, const void* pseb1, const void* psew2, const void* pseb2,
    float* __restrict__ cvt, float* __restrict__ means, int* __restrict__ bar,
    float* __restrict__ al_s, float* __restrict__ al_d,
    unsigned short* __restrict__ wb,
    unsigned short* __restrict__ xT16,
    unsigned short* __restrict__ xf16,
    unsigned short* __restrict__ h16,
    unsigned short* __restrict__ idb16,
    void* __restrict__ outp)
{
    __shared__ SmemAll sm;
    const int tid = threadIdx.x;
    const int bid = blockIdx.x;
    const bool f32 = probe_f32(xp);

    const int lane = tid & 63, wv = tid >> 6;
    const int wm = wv >> 1, wn = wv & 1;
    const int lr = lane & 15, quad = lane >> 4;

    // ============================ phase 0: prep + transpose ============================
    for (int i = bid * 256 + tid; i < B_WEND; i += GRID * 256) {
        const void* s; int o;
        if      (i < B_WID)   { s = pwin;  o = i - B_WIN; }
        else if (i < B_WGAT)  { s = pwid;  o = i - B_WID; }
        else if (i < B_WOUT)  { s = pwgat; o = i - B_WGAT; }
        else                  { s = pwout; o = i - B_WOUT; }
        wb[i] = f32 ? f2b(((const float*)s)[o]) : ((const unsigned short*)s)[o];
    }
    for (int i = bid * 256 + tid; i < 512; i += GRID * 256) {
        float sc = ldf(pbng, i, f32) * rsqrtf(ldf(pbnv, i, f32) + 1e-5f);
        cvt[C_BNA + i] = sc;
        cvt[C_BNB + i] = (ldf(pgbias, i, f32) - ldf(pbnm, i, f32)) * sc + ldf(pbnb, i, f32);
        cvt[C_ASRC + i] = ldf(pasrc, i, f32);
        cvt[C_ADST + i] = ldf(padst, i, f32);
    }
    for (int i = bid * 256 + tid; i < 16384; i += GRID * 256) {
        cvt[C_SEW1 + i] = ldf(psew1, i, f32);
        cvt[C_SEW2 + i] = ldf(psew2, i, f32);
    }
    for (int i = bid * 256 + tid; i < 64; i += GRID * 256)  cvt[C_SEB1 + i] = ldf(pseb1, i, f32);
    for (int i = bid * 256 + tid; i < 256; i += GRID * 256) cvt[C_SEB2 + i] = ldf(pseb2, i, f32);

    if (bid < 400) {   // transpose x -> bf16 [25600][128]
        const int n0 = bid * 64;
        const int nl = tid & 63;
#pragma unroll
        for (int i = 0; i < 32; ++i) {
            int c = i * 4 + (tid >> 6);
            long idx = (long)c * NN + n0 + nl;
            sm.t.T[nl * 136 + c] = f32 ? f2b(((const float*)xp)[idx]) : xp[idx];
        }
        __syncthreads();
#pragma unroll
        for (int i = 0; i < 4; ++i) {
            int n = tid >> 2, c0 = (tid & 3) * 32 + i * 8;
            uint4 v = *(const uint4*)&sm.t.T[n * 136 + c0];
            *(uint4*)(xT16 + (long)(n0 + n) * 128 + c0) = v;
        }
    }
    grid_bar(bar, 1 * GRID);

    // ============================ phase 1: gemm_x2 (K=128, dual B) ============================
    if (bid < 800) {
        const int m0 = (bid >> 2) * 128, o0 = (bid & 3) * 64;
        ffrag ai[4][2], ad[4][2];
#pragma unroll
        for (int mt = 0; mt < 4; ++mt)
#pragma unroll
            for (int nt = 0; nt < 2; ++nt) { ai[mt][nt] = (ffrag){0,0,0,0}; ad[mt][nt] = (ffrag){0,0,0,0}; }
        for (int k0 = 0; k0 < 128; k0 += 32) {
#pragma unroll
            for (int c = tid; c < 512; c += 256) {
                int row = c >> 2, q = c & 3;
                uint4 v = *(const uint4*)(xT16 + (long)(m0 + row) * 128 + k0 + q * 8);
                *(uint4*)&sm.g2.As[row * 40 + q * 8] = v;
            }
            {
                int row = tid >> 2, q = tid & 3;
                uint4 vi = *(const uint4*)(wb + B_WIN + (long)(o0 + row) * 128 + k0 + q * 8);
                uint4 vd = *(const uint4*)(wb + B_WID + (long)(o0 + row) * 128 + k0 + q * 8);
                *(uint4*)&sm.g2.Bi[row * 40 + q * 8] = vi;
                *(uint4*)&sm.g2.Bd[row * 40 + q * 8] = vd;
            }
            __syncthreads();
            bfrag a[4], bi[2], bd[2];
#pragma unroll
            for (int mt = 0; mt < 4; ++mt)
                a[mt] = *(const bfrag*)&sm.g2.As[(wm * 64 + mt * 16 + lr) * 40 + quad * 8];
#pragma unroll
            for (int nt = 0; nt < 2; ++nt) {
                bi[nt] = *(const bfrag*)&sm.g2.Bi[(wn * 32 + nt * 16 + lr) * 40 + quad * 8];
                bd[nt] = *(const bfrag*)&sm.g2.Bd[(wn * 32 + nt * 16 + lr) * 40 + quad * 8];
            }
#pragma unroll
            for (int mt = 0; mt < 4; ++mt)
#pragma unroll
                for (int nt = 0; nt < 2; ++nt) {
                    ai[mt][nt] = __builtin_amdgcn_mfma_f32_16x16x32_bf16(a[mt], bi[nt], ai[mt][nt], 0, 0, 0);
                    ad[mt][nt] = __builtin_amdgcn_mfma_f32_16x16x32_bf16(a[mt], bd[nt], ad[mt][nt], 0, 0, 0);
                }
            __syncthreads();
        }
#pragma unroll
        for (int mt = 0; mt < 4; ++mt)
#pragma unroll
            for (int nt = 0; nt < 2; ++nt)
#pragma unroll
                for (int r = 0; r < 4; ++r) {
                    int m = m0 + wm * 64 + mt * 16 + quad * 4 + r;
                    int o = o0 + wn * 32 + nt * 16 + lr;
                    xf16[(long)m * C2 + o]  = f2b(ai[mt][nt][r]);
                    idb16[(long)m * C2 + o] = f2b(ad[mt][nt][r]);
                }
    }
    grid_bar(bar, 2 * GRID);

    // ============================ hops + out-GEMM ============================
    for (int phase = 0; phase < 3; ++phase) {
        // ---- gemm_nn: h16 = xf16 @ W^T; epilogue attn (phase<2) or colsum (phase==2)
        const unsigned short* W = (phase < 2) ? (wb + B_WGAT + phase * 65536) : (wb + B_WOUT);
        {
            const int m0 = (bid >> 2) * 128, o0 = (bid & 3) * 64;
            ffrag acc[4][2];
#pragma unroll
            for (int mt = 0; mt < 4; ++mt)
#pragma unroll
                for (int nt = 0; nt < 2; ++nt) acc[mt][nt] = (ffrag){0,0,0,0};
            for (int k0 = 0; k0 < 256; k0 += 32) {
#pragma unroll
                for (int c = tid; c < 512; c += 256) {
                    int row = c >> 2, q = c & 3;
                    uint4 v = *(const uint4*)(xf16 + (long)(m0 + row) * 256 + k0 + q * 8);
                    *(uint4*)&sm.g.As[row * 40 + q * 8] = v;
                }
                {
                    int row = tid >> 2, q = tid & 3;
                    uint4 v = *(const uint4*)(W + (long)(o0 + row) * 256 + k0 + q * 8);
                    *(uint4*)&sm.g.Bs[row * 40 + q * 8] = v;
                }
                __syncthreads();
                bfrag a[4], b[2];
#pragma unroll
                for (int mt = 0; mt < 4; ++mt)
                    a[mt] = *(const bfrag*)&sm.g.As[(wm * 64 + mt * 16 + lr) * 40 + quad * 8];
#pragma unroll
                for (int nt = 0; nt < 2; ++nt)
                    b[nt] = *(const bfrag*)&sm.g.Bs[(wn * 32 + nt * 16 + lr) * 40 + quad * 8];
#pragma unroll
                for (int mt = 0; mt < 4; ++mt)
#pragma unroll
                    for (int nt = 0; nt < 2; ++nt)
                        acc[mt][nt] = __builtin_amdgcn_mfma_f32_16x16x32_bf16(a[mt], b[nt], acc[mt][nt], 0, 0, 0);
                __syncthreads();
            }
#pragma unroll
            for (int mt = 0; mt < 4; ++mt)
#pragma unroll
                for (int nt = 0; nt < 2; ++nt)
#pragma unroll
                    for (int r = 0; r < 4; ++r) {
                        int m = m0 + wm * 64 + mt * 16 + quad * 4 + r;
                        int o = o0 + wn * 32 + nt * 16 + lr;
                        h16[(long)m * C2 + o] = f2b(acc[mt][nt][r]);
                    }
            if (phase < 2) {
                const float* asrc = cvt + C_ASRC + phase * 256;
                const float* adst = cvt + C_ADST + phase * 256;
                const int head = (bid & 3) * 2 + wn;
                const float as0 = asrc[head * 32 + lr], as1 = asrc[head * 32 + 16 + lr];
                const float ad0 = adst[head * 32 + lr], ad1 = adst[head * 32 + 16 + lr];
#pragma unroll
                for (int mt = 0; mt < 4; ++mt)
#pragma unroll
                    for (int r = 0; r < 4; ++r) {
                        float ps = acc[mt][0][r] * as0 + acc[mt][1][r] * as1;
                        float pd = acc[mt][0][r] * ad0 + acc[mt][1][r] * ad1;
#pragma unroll
                        for (int sh = 1; sh < 16; sh <<= 1) {
                            ps += __shfl_xor(ps, sh);
                            pd += __shfl_xor(pd, sh);
                        }
                        if (lr == 0) {
                            int m = m0 + wm * 64 + mt * 16 + quad * 4 + r;
                            al_s[m * 8 + head] = ps;
                            al_d[m * 8 + head] = pd;
                        }
                    }
            } else {
                const int o0c = (bid & 3) * 64;
#pragma unroll
                for (int nt = 0; nt < 2; ++nt) {
                    float p = 0.f;
#pragma unroll
                    for (int mt = 0; mt < 4; ++mt)
#pragma unroll
                        for (int r = 0; r < 4; ++r) p += acc[mt][nt][r];
                    p += __shfl_xor(p, 16);
                    p += __shfl_xor(p, 32);
                    if (quad == 0) atomicAdd(&means[o0c + wn * 32 + nt * 16 + lr], p);
                }
            }
        }
        grid_bar(bar, (3 + 2 * phase) * GRID);
        if (phase == 2) break;

        // ---- aggregate: segment softmax + 11-tap gather + BN + ReLU + residual
        {
            const int SI[11] = { 1, 1, 1, 0, 0, -1, -1, -1, -2,  0, 0};
            const int SJ[11] = { 1, 0,-1, 1,-1,  1,  0, -1,  0, -2, 0};
            const float* bnA = cvt + C_BNA + phase * 256;
            const float* bnB = cvt + C_BNB + phase * 256;
            const int ln = tid >> 5;
            const int l = tid & 31;
            for (int g8 = bid; g8 < 3200; g8 += GRID) {
                const int n = g8 * 8 + ln;
                const int i = n / WW, j = n % WW;
                for (int idx = tid; idx < 704; idx += 256) {
                    int lln = idx / 88, rem = idx - lln * 88;
                    int k = rem >> 3, hh = rem & 7;
                    int nn2 = g8 * 8 + lln;
                    int ii = nn2 / WW, jj = nn2 - ii * WW;
                    int si = ii + SI[k], sj = jj + SJ[k];
                    bool okk = (si >= 0) & (si < HH) & (sj >= 0) & (sj < WW);
                    sm.a.es[lln][k][hh] = okk ? al_s[(si * WW + sj) * 8 + hh] : -1e30f;
                }
                __syncthreads();
                if (l < 8) {
                    const int hd = l;
                    const float ald = al_d[n * 8 + hd];
                    float e[11];
                    float mx = -1e30f;
#pragma unroll
                    for (int k = 0; k < 11; ++k) {
                        float v = sm.a.es[ln][k][hd] + ald;
                        v = v > 0.f ? v : 0.2f * v;
                        e[k] = v;
                        mx = fmaxf(mx, v);
                    }
                    float denom = 0.f;
#pragma unroll
                    for (int k = 0; k < 11; ++k) {
                        float p = __expf(e[k] - mx);
                        e[k] = p;
                        denom += p;
                    }
                    const float inv = 1.f / (denom + 1e-16f);
#pragma unroll
                    for (int k = 0; k < 11; ++k) sm.a.alpha[ln][k][hd] = e[k] * inv;
                }
                __syncthreads();
                const int c8 = l * 8;
                const int hd = l >> 2;
                int srcn[11];
#pragma unroll
                for (int k = 0; k < 11; ++k) {
                    int si = i + SI[k], sj = j + SJ[k];
                    bool ok = (si >= 0) & (si < HH) & (sj >= 0) & (sj < WW);
                    srcn[k] = ok ? si * WW + sj : n;
                }
                float a0=0.f,a1=0.f,a2=0.f,a3=0.f,a4=0.f,a5=0.f,a6=0.f,a7=0.f;
#pragma unroll
                for (int k = 0; k < 11; ++k) {
                    float al = sm.a.alpha[ln][k][hd];
                    uint4 hv = *(const uint4*)(h16 + (long)srcn[k] * C2 + c8);
                    a0 += al * lo16f(hv.x); a1 += al * hi16f(hv.x);
                    a2 += al * lo16f(hv.y); a3 += al * hi16f(hv.y);
                    a4 += al * lo16f(hv.z); a5 += al * hi16f(hv.z);
                    a6 += al * lo16f(hv.w); a7 += al * hi16f(hv.w);
                }
                float acc8[8] = {a0,a1,a2,a3,a4,a5,a6,a7};
                uint4 rv = *(const uint4*)(xf16 + (long)n * C2 + c8);
                float res[8] = {lo16f(rv.x),hi16f(rv.x),lo16f(rv.y),hi16f(rv.y),
                                lo16f(rv.z),hi16f(rv.z),lo16f(rv.w),hi16f(rv.w)};
                float out[8];
#pragma unroll
                for (int q = 0; q < 8; ++q) {
                    int c = c8 + q;
                    float g = acc8[q] * bnA[c] + bnB[c];
                    out[q] = fmaxf(g, 0.f) + res[q];
                }
                ushort4 o16a, o16b;
                o16a.x = f2b(out[0]); o16a.y = f2b(out[1]); o16a.z = f2b(out[2]); o16a.w = f2b(out[3]);
                o16b.x = f2b(out[4]); o16b.y = f2b(out[5]); o16b.z = f2b(out[6]); o16b.w = f2b(out[7]);
                *(ushort4*)(xf16 + (long)n * C2 + c8)     = o16a;
                *(ushort4*)(xf16 + (long)n * C2 + c8 + 4) = o16b;
                __syncthreads();
            }
        }
        grid_bar(bar, (4 + 2 * phase) * GRID);
    }

    // ============================ phase 7: SE + final ============================
    {
        sm.f.mv[tid] = means[tid] * (1.0f / 25600.0f);
        __syncthreads();
        if (tid < 64) {
            const float* w1 = cvt + C_SEW1 + tid * 256;
            float s = cvt[C_SEB1 + tid];
            for (int cc = 0; cc < 256; cc += 4) {
                float4 wv = *(const float4*)(w1 + cc);
                s += wv.x * sm.f.mv[cc] + wv.y * sm.f.mv[cc+1] + wv.z * sm.f.mv[cc+2] + wv.w * sm.f.mv[cc+3];
            }
            sm.f.hv[tid] = fmaxf(s, 0.f);
        }
        __syncthreads();
        {
            const float* w2 = cvt + C_SEW2 + tid * 64;
            float s = cvt[C_SEB2 + tid];
            for (int k = 0; k < 64; k += 4) {
                float4 wv = *(const float4*)(w2 + k);
                s += wv.x * sm.f.hv[k] + wv.y * sm.f.hv[k+1] + wv.z * sm.f.hv[k+2] + wv.w * sm.f.hv[k+3];
            }
            sm.f.sv[tid] = 1.0f / (1.0f + __expf(-s));
        }
        __syncthreads();
        for (int w = bid; w < 1600; w += GRID) {
            const int n0 = (w >> 2) * 64, c0 = (w & 3) * 64;
#pragma unroll
            for (int it = 0; it < 16; ++it) {
                int e = tid + it * 256;
                int nn = e >> 6, cc = e & 63;
                long idx = (long)(n0 + nn) * C2 + c0 + cc;
                sm.f.T[cc][nn] = b2f(h16[idx]) * sm.f.sv[c0 + cc] + b2f(idb16[idx]);
            }
            __syncthreads();
#pragma unroll
            for (int it = 0; it < 16; ++it) {
                int e = tid + it * 256;
                int cc = e >> 6, nn = e & 63;
                long idx = (long)(c0 + cc) * NN + n0 + nn;
                float v = sm.f.T[cc][nn];
                if (f32) ((float*)outp)[idx] = v;
                else     ((unsigned short*)outp)[idx] = f2b(v);
            }
            __syncthreads();
        }
    }
}

extern "C" void kernel_launch(void* const* d_in, const int* in_sizes, int n_in,
                              void* d_out, int out_size, void* d_ws, size_t ws_size,
                              hipStream_t stream) {
    float* ws = (float*)d_ws;
    float* cvt   = ws;                          // C_END
    float* means = ws + 35200;                  // 256 (64-aligned)
    int*   bar   = (int*)(means + 256);         // barrier counter
    float* als   = means + 320;                 // 204800
    float* ald   = als + 204800;
    unsigned short* wb16  = (unsigned short*)(ald + 204800);  // 262144
    unsigned short* xT16  = wb16 + B_WEND;                    // 25600*128
    unsigned short* xf16  = xT16 + NN * 128;                  // 25600*256 (residual)
    unsigned short* h16   = xf16 + NN * 256;                  // 25600*256 (h / y)
    unsigned short* idb16 = h16 + NN * 256;                   // 25600*256

    // zero means + bar in one memset (contiguous 320 floats incl. bar slot)
    hipMemsetAsync(means, 0, 320 * sizeof(float), stream);

    mega_kernel<<<GRID, 256, 0, stream>>>(
        (const unsigned short*)d_in[0],
        d_in[1], d_in[2], d_in[3], d_in[11],
        d_in[4], d_in[5], d_in[6], d_in[7], d_in[8], d_in[9], d_in[10],
        d_in[12], d_in[13], d_in[14], d_in[15],
        cvt, means, bar, als, ald,
        wb16, xT16, xf16, h16, idb16, d_out);
}

// Round 7
// 895.699 us; speedup vs baseline: 1.6082x; 1.6082x over previous
//
#include <hip/hip_runtime.h>

#define NN 25600      // nodes = 160*160
#define HH 160
#define WW 160
#define C2 256
#define GRID 800      // co-resident: launch_bounds(256,4) guarantees >=1024 capacity

// ---- bf16 weight pack offsets (ushorts) ----
#define B_WIN   0
#define B_WID   32768
#define B_WGAT  65536      // 2 layers x 65536
#define B_WOUT  196608
#define B_WEND  262144

// ---- small fp32 param offsets inside cvt (floats) ----
#define C_BNA   0          // 2x256 BN scale
#define C_BNB   512        // 2x256 BN shift (bias/mean folded)
#define C_ASRC  1024       // 2x256
#define C_ADST  1536       // 2x256
#define C_SEW1  2048       // 64x256
#define C_SEB1  18432      // 64
#define C_SEW2  18496      // 256x64
#define C_SEB2  34880      // 256
#define C_END   35136

typedef __attribute__((ext_vector_type(8))) short bfrag;   // 8 bf16 (4 VGPRs)
typedef __attribute__((ext_vector_type(4))) float ffrag;   // 4 fp32 acc

struct SmemG2 { unsigned short As[128*40], Bi[64*40], Bd[64*40]; }; // 20480 B
struct SmemG  { unsigned short As[128*40], Bs[64*40]; };            // 15360 B
struct SmemAg { float es[8][11][8]; float alpha[8][11][8]; };       // 5632 B
struct SmemTr { unsigned short T[64*136]; };                        // 17408 B
struct SmemFi { float T[64][65]; float mv[256]; float hv[64]; float sv[256]; }; // 18944 B
union  SmemAll { SmemG2 g2; SmemG g; SmemAg a; SmemTr t; SmemFi f; };

__device__ __forceinline__ float b2f(unsigned short u) {
    union { unsigned int ui; float f; } v; v.ui = ((unsigned int)u) << 16; return v.f;
}
__device__ __forceinline__ unsigned short f2b(float f) {
    union { float f; unsigned int u; } v; v.f = f;
    unsigned int u = v.u;
    unsigned int r = (u + 0x7FFFu + ((u >> 16) & 1u)) >> 16;
    return (unsigned short)r;
}
__device__ __forceinline__ float lo16f(unsigned int w) {
    union { unsigned int ui; float f; } v; v.ui = w << 16; return v.f;
}
__device__ __forceinline__ float hi16f(unsigned int w) {
    union { unsigned int ui; float f; } v; v.ui = w & 0xFFFF0000u; return v.f;
}
// Wave-uniform dtype probe on first 512 halfwords of x.
__device__ __forceinline__ bool probe_f32(const unsigned short* __restrict__ x) {
    int l = threadIdx.x & 63;
    bool wild = false;
#pragma unroll
    for (int i = 0; i < 8; ++i) {
        float v = b2f(x[l * 8 + i]);
        wild |= !(fabsf(v) < 1e6f);
    }
    return __any(wild);
}
__device__ __forceinline__ float ldf(const void* p, long i, bool f32) {
    return f32 ? ((const float*)p)[i] : b2f(((const unsigned short*)p)[i]);
}

// Grid barrier (FIXED): release on arrival, RELAXED spin (no per-poll cache
// invalidate!), a single agent-scope acquire fence on exit. R6's bug was an
// ACQUIRE load in the spin loop -> buffer_inv (L1+XCD-L2 invalidate) per poll
// from 800 blocks = continuous cache thrash, 5.6x regression.
__device__ __forceinline__ void grid_bar(int* bar, int target) {
    __syncthreads();
    if (threadIdx.x == 0) {
        __hip_atomic_fetch_add(bar, 1, __ATOMIC_RELEASE, __HIP_MEMORY_SCOPE_AGENT);
        while (__hip_atomic_load(bar, __ATOMIC_RELAXED, __HIP_MEMORY_SCOPE_AGENT) < target)
            __builtin_amdgcn_s_sleep(2);
        __builtin_amdgcn_fence(__ATOMIC_ACQUIRE, "agent");
    }
    __syncthreads();
}

__global__ __launch_bounds__(256, 4) void mega_kernel(
    const unsigned short* __restrict__ xp,   // x raw (probe + transpose src)
    const void* pwid, const void* pwin, const void* pwgat, const void* pwout,
    const void* pasrc, const void* padst, const void* pgbias,
    const void* pbng, const void* pbnb, const void* pbnm, const void* pbnv,
    const void* psew1, const void* pseb1, const void* psew2, const void* pseb2,
    float* __restrict__ cvt, float* __restrict__ means, int* __restrict__ bar,
    float* __restrict__ al_s, float* __restrict__ al_d,
    unsigned short* __restrict__ wb,
    unsigned short* __restrict__ xT16,
    unsigned short* __restrict__ xf16,
    unsigned short* __restrict__ h16,
    unsigned short* __restrict__ idb16,
    void* __restrict__ outp)
{
    __shared__ SmemAll sm;
    const int tid = threadIdx.x;
    const int bid = blockIdx.x;
    const bool f32 = probe_f32(xp);

    const int lane = tid & 63, wv = tid >> 6;
    const int wm = wv >> 1, wn = wv & 1;
    const int lr = lane & 15, quad = lane >> 4;

    // ============================ phase 0: prep + transpose ============================
    for (int i = bid * 256 + tid; i < B_WEND; i += GRID * 256) {
        const void* s; int o;
        if      (i < B_WID)   { s = pwin;  o = i - B_WIN; }
        else if (i < B_WGAT)  { s = pwid;  o = i - B_WID; }
        else if (i < B_WOUT)  { s = pwgat; o = i - B_WGAT; }
        else                  { s = pwout; o = i - B_WOUT; }
        wb[i] = f32 ? f2b(((const float*)s)[o]) : ((const unsigned short*)s)[o];
    }
    for (int i = bid * 256 + tid; i < 512; i += GRID * 256) {
        float sc = ldf(pbng, i, f32) * rsqrtf(ldf(pbnv, i, f32) + 1e-5f);
        cvt[C_BNA + i] = sc;
        cvt[C_BNB + i] = (ldf(pgbias, i, f32) - ldf(pbnm, i, f32)) * sc + ldf(pbnb, i, f32);
        cvt[C_ASRC + i] = ldf(pasrc, i, f32);
        cvt[C_ADST + i] = ldf(padst, i, f32);
    }
    for (int i = bid * 256 + tid; i < 16384; i += GRID * 256) {
        cvt[C_SEW1 + i] = ldf(psew1, i, f32);
        cvt[C_SEW2 + i] = ldf(psew2, i, f32);
    }
    for (int i = bid * 256 + tid; i < 64; i += GRID * 256)  cvt[C_SEB1 + i] = ldf(pseb1, i, f32);
    for (int i = bid * 256 + tid; i < 256; i += GRID * 256) cvt[C_SEB2 + i] = ldf(pseb2, i, f32);

    if (bid < 400) {   // transpose x -> bf16 [25600][128]
        const int n0 = bid * 64;
        const int nl = tid & 63;
#pragma unroll
        for (int i = 0; i < 32; ++i) {
            int c = i * 4 + (tid >> 6);
            long idx = (long)c * NN + n0 + nl;
            sm.t.T[nl * 136 + c] = f32 ? f2b(((const float*)xp)[idx]) : xp[idx];
        }
        __syncthreads();
#pragma unroll
        for (int i = 0; i < 4; ++i) {
            int n = tid >> 2, c0 = (tid & 3) * 32 + i * 8;
            uint4 v = *(const uint4*)&sm.t.T[n * 136 + c0];
            *(uint4*)(xT16 + (long)(n0 + n) * 128 + c0) = v;
        }
    }
    grid_bar(bar, 1 * GRID);

    // ============================ phase 1: gemm_x2 (K=128, dual B) ============================
    if (bid < 800) {
        const int m0 = (bid >> 2) * 128, o0 = (bid & 3) * 64;
        ffrag ai[4][2], ad[4][2];
#pragma unroll
        for (int mt = 0; mt < 4; ++mt)
#pragma unroll
            for (int nt = 0; nt < 2; ++nt) { ai[mt][nt] = (ffrag){0,0,0,0}; ad[mt][nt] = (ffrag){0,0,0,0}; }
        for (int k0 = 0; k0 < 128; k0 += 32) {
#pragma unroll
            for (int c = tid; c < 512; c += 256) {
                int row = c >> 2, q = c & 3;
                uint4 v = *(const uint4*)(xT16 + (long)(m0 + row) * 128 + k0 + q * 8);
                *(uint4*)&sm.g2.As[row * 40 + q * 8] = v;
            }
            {
                int row = tid >> 2, q = tid & 3;
                uint4 vi = *(const uint4*)(wb + B_WIN + (long)(o0 + row) * 128 + k0 + q * 8);
                uint4 vd = *(const uint4*)(wb + B_WID + (long)(o0 + row) * 128 + k0 + q * 8);
                *(uint4*)&sm.g2.Bi[row * 40 + q * 8] = vi;
                *(uint4*)&sm.g2.Bd[row * 40 + q * 8] = vd;
            }
            __syncthreads();
            bfrag a[4], bi[2], bd[2];
#pragma unroll
            for (int mt = 0; mt < 4; ++mt)
                a[mt] = *(const bfrag*)&sm.g2.As[(wm * 64 + mt * 16 + lr) * 40 + quad * 8];
#pragma unroll
            for (int nt = 0; nt < 2; ++nt) {
                bi[nt] = *(const bfrag*)&sm.g2.Bi[(wn * 32 + nt * 16 + lr) * 40 + quad * 8];
                bd[nt] = *(const bfrag*)&sm.g2.Bd[(wn * 32 + nt * 16 + lr) * 40 + quad * 8];
            }
#pragma unroll
            for (int mt = 0; mt < 4; ++mt)
#pragma unroll
                for (int nt = 0; nt < 2; ++nt) {
                    ai[mt][nt] = __builtin_amdgcn_mfma_f32_16x16x32_bf16(a[mt], bi[nt], ai[mt][nt], 0, 0, 0);
                    ad[mt][nt] = __builtin_amdgcn_mfma_f32_16x16x32_bf16(a[mt], bd[nt], ad[mt][nt], 0, 0, 0);
                }
            __syncthreads();
        }
#pragma unroll
        for (int mt = 0; mt < 4; ++mt)
#pragma unroll
            for (int nt = 0; nt < 2; ++nt)
#pragma unroll
                for (int r = 0; r < 4; ++r) {
                    int m = m0 + wm * 64 + mt * 16 + quad * 4 + r;
                    int o = o0 + wn * 32 + nt * 16 + lr;
                    xf16[(long)m * C2 + o]  = f2b(ai[mt][nt][r]);
                    idb16[(long)m * C2 + o] = f2b(ad[mt][nt][r]);
                }
    }
    grid_bar(bar, 2 * GRID);

    // ============================ hops + out-GEMM ============================
    for (int phase = 0; phase < 3; ++phase) {
        // ---- gemm_nn: h16 = xf16 @ W^T; epilogue attn (phase<2) or colsum (phase==2)
        const unsigned short* W = (phase < 2) ? (wb + B_WGAT + phase * 65536) : (wb + B_WOUT);
        {
            const int m0 = (bid >> 2) * 128, o0 = (bid & 3) * 64;
            ffrag acc[4][2];
#pragma unroll
            for (int mt = 0; mt < 4; ++mt)
#pragma unroll
                for (int nt = 0; nt < 2; ++nt) acc[mt][nt] = (ffrag){0,0,0,0};
            for (int k0 = 0; k0 < 256; k0 += 32) {
#pragma unroll
                for (int c = tid; c < 512; c += 256) {
                    int row = c >> 2, q = c & 3;
                    uint4 v = *(const uint4*)(xf16 + (long)(m0 + row) * 256 + k0 + q * 8);
                    *(uint4*)&sm.g.As[row * 40 + q * 8] = v;
                }
                {
                    int row = tid >> 2, q = tid & 3;
                    uint4 v = *(const uint4*)(W + (long)(o0 + row) * 256 + k0 + q * 8);
                    *(uint4*)&sm.g.Bs[row * 40 + q * 8] = v;
                }
                __syncthreads();
                bfrag a[4], b[2];
#pragma unroll
                for (int mt = 0; mt < 4; ++mt)
                    a[mt] = *(const bfrag*)&sm.g.As[(wm * 64 + mt * 16 + lr) * 40 + quad * 8];
#pragma unroll
                for (int nt = 0; nt < 2; ++nt)
                    b[nt] = *(const bfrag*)&sm.g.Bs[(wn * 32 + nt * 16 + lr) * 40 + quad * 8];
#pragma unroll
                for (int mt = 0; mt < 4; ++mt)
#pragma unroll
                    for (int nt = 0; nt < 2; ++nt)
                        acc[mt][nt] = __builtin_amdgcn_mfma_f32_16x16x32_bf16(a[mt], b[nt], acc[mt][nt], 0, 0, 0);
                __syncthreads();
            }
#pragma unroll
            for (int mt = 0; mt < 4; ++mt)
#pragma unroll
                for (int nt = 0; nt < 2; ++nt)
#pragma unroll
                    for (int r = 0; r < 4; ++r) {
                        int m = m0 + wm * 64 + mt * 16 + quad * 4 + r;
                        int o = o0 + wn * 32 + nt * 16 + lr;
                        h16[(long)m * C2 + o] = f2b(acc[mt][nt][r]);
                    }
            if (phase < 2) {
                const float* asrc = cvt + C_ASRC + phase * 256;
                const float* adst = cvt + C_ADST + phase * 256;
                const int head = (bid & 3) * 2 + wn;
                const float as0 = asrc[head * 32 + lr], as1 = asrc[head * 32 + 16 + lr];
                const float ad0 = adst[head * 32 + lr], ad1 = adst[head * 32 + 16 + lr];
#pragma unroll
                for (int mt = 0; mt < 4; ++mt)
#pragma unroll
                    for (int r = 0; r < 4; ++r) {
                        float ps = acc[mt][0][r] * as0 + acc[mt][1][r] * as1;
                        float pd = acc[mt][0][r] * ad0 + acc[mt][1][r] * ad1;
#pragma unroll
                        for (int sh = 1; sh < 16; sh <<= 1) {
                            ps += __shfl_xor(ps, sh);
                            pd += __shfl_xor(pd, sh);
                        }
                        if (lr == 0) {
                            int m = m0 + wm * 64 + mt * 16 + quad * 4 + r;
                            al_s[m * 8 + head] = ps;
                            al_d[m * 8 + head] = pd;
                        }
                    }
            } else {
                const int o0c = (bid & 3) * 64;
#pragma unroll
                for (int nt = 0; nt < 2; ++nt) {
                    float p = 0.f;
#pragma unroll
                    for (int mt = 0; mt < 4; ++mt)
#pragma unroll
                        for (int r = 0; r < 4; ++r) p += acc[mt][nt][r];
                    p += __shfl_xor(p, 16);
                    p += __shfl_xor(p, 32);
                    if (quad == 0) atomicAdd(&means[o0c + wn * 32 + nt * 16 + lr], p);
                }
            }
        }
        grid_bar(bar, (3 + 2 * phase) * GRID);
        if (phase == 2) break;

        // ---- aggregate: segment softmax + 11-tap gather + BN + ReLU + residual
        {
            const int SI[11] = { 1, 1, 1, 0, 0, -1, -1, -1, -2,  0, 0};
            const int SJ[11] = { 1, 0,-1, 1,-1,  1,  0, -1,  0, -2, 0};
            const float* bnA = cvt + C_BNA + phase * 256;
            const float* bnB = cvt + C_BNB + phase * 256;
            const int ln = tid >> 5;
            const int l = tid & 31;
            for (int g8 = bid; g8 < 3200; g8 += GRID) {
                const int n = g8 * 8 + ln;
                const int i = n / WW, j = n % WW;
                for (int idx = tid; idx < 704; idx += 256) {
                    int lln = idx / 88, rem = idx - lln * 88;
                    int k = rem >> 3, hh = rem & 7;
                    int nn2 = g8 * 8 + lln;
                    int ii = nn2 / WW, jj = nn2 - ii * WW;
                    int si = ii + SI[k], sj = jj + SJ[k];
                    bool okk = (si >= 0) & (si < HH) & (sj >= 0) & (sj < WW);
                    sm.a.es[lln][k][hh] = okk ? al_s[(si * WW + sj) * 8 + hh] : -1e30f;
                }
                __syncthreads();
                if (l < 8) {
                    const int hd = l;
                    const float ald = al_d[n * 8 + hd];
                    float e[11];
                    float mx = -1e30f;
#pragma unroll
                    for (int k = 0; k < 11; ++k) {
                        float v = sm.a.es[ln][k][hd] + ald;
                        v = v > 0.f ? v : 0.2f * v;
                        e[k] = v;
                        mx = fmaxf(mx, v);
                    }
                    float denom = 0.f;
#pragma unroll
                    for (int k = 0; k < 11; ++k) {
                        float p = __expf(e[k] - mx);
                        e[k] = p;
                        denom += p;
                    }
                    const float inv = 1.f / (denom + 1e-16f);
#pragma unroll
                    for (int k = 0; k < 11; ++k) sm.a.alpha[ln][k][hd] = e[k] * inv;
                }
                __syncthreads();
                const int c8 = l * 8;
                const int hd = l >> 2;
                int srcn[11];
#pragma unroll
                for (int k = 0; k < 11; ++k) {
                    int si = i + SI[k], sj = j + SJ[k];
                    bool ok = (si >= 0) & (si < HH) & (sj >= 0) & (sj < WW);
                    srcn[k] = ok ? si * WW + sj : n;
                }
                float a0=0.f,a1=0.f,a2=0.f,a3=0.f,a4=0.f,a5=0.f,a6=0.f,a7=0.f;
#pragma unroll
                for (int k = 0; k < 11; ++k) {
                    float al = sm.a.alpha[ln][k][hd];
                    uint4 hv = *(const uint4*)(h16 + (long)srcn[k] * C2 + c8);
                    a0 += al * lo16f(hv.x); a1 += al * hi16f(hv.x);
                    a2 += al * lo16f(hv.y); a3 += al * hi16f(hv.y);
                    a4 += al * lo16f(hv.z); a5 += al * hi16f(hv.z);
                    a6 += al * lo16f(hv.w); a7 += al * hi16f(hv.w);
                }
                float acc8[8] = {a0,a1,a2,a3,a4,a5,a6,a7};
                uint4 rv = *(const uint4*)(xf16 + (long)n * C2 + c8);
                float res[8] = {lo16f(rv.x),hi16f(rv.x),lo16f(rv.y),hi16f(rv.y),
                                lo16f(rv.z),hi16f(rv.z),lo16f(rv.w),hi16f(rv.w)};
                float out[8];
#pragma unroll
                for (int q = 0; q < 8; ++q) {
                    int c = c8 + q;
                    float g = acc8[q] * bnA[c] + bnB[c];
                    out[q] = fmaxf(g, 0.f) + res[q];
                }
                ushort4 o16a, o16b;
                o16a.x = f2b(out[0]); o16a.y = f2b(out[1]); o16a.z = f2b(out[2]); o16a.w = f2b(out[3]);
                o16b.x = f2b(out[4]); o16b.y = f2b(out[5]); o16b.z = f2b(out[6]); o16b.w = f2b(out[7]);
                *(ushort4*)(xf16 + (long)n * C2 + c8)     = o16a;
                *(ushort4*)(xf16 + (long)n * C2 + c8 + 4) = o16b;
                __syncthreads();
            }
        }
        grid_bar(bar, (4 + 2 * phase) * GRID);
    }

    // ============================ phase 7: SE + final ============================
    {
        sm.f.mv[tid] = means[tid] * (1.0f / 25600.0f);
        __syncthreads();
        if (tid < 64) {
            const float* w1 = cvt + C_SEW1 + tid * 256;
            float s = cvt[C_SEB1 + tid];
            for (int cc = 0; cc < 256; cc += 4) {
                float4 wv = *(const float4*)(w1 + cc);
                s += wv.x * sm.f.mv[cc] + wv.y * sm.f.mv[cc+1] + wv.z * sm.f.mv[cc+2] + wv.w * sm.f.mv[cc+3];
            }
            sm.f.hv[tid] = fmaxf(s, 0.f);
        }
        __syncthreads();
        {
            const float* w2 = cvt + C_SEW2 + tid * 64;
            float s = cvt[C_SEB2 + tid];
            for (int k = 0; k < 64; k += 4) {
                float4 wv = *(const float4*)(w2 + k);
                s += wv.x * sm.f.hv[k] + wv.y * sm.f.hv[k+1] + wv.z * sm.f.hv[k+2] + wv.w * sm.f.hv[k+3];
            }
            sm.f.sv[tid] = 1.0f / (1.0f + __expf(-s));
        }
        __syncthreads();
        for (int w = bid; w < 1600; w += GRID) {
            const int n0 = (w >> 2) * 64, c0 = (w & 3) * 64;
#pragma unroll
            for (int it = 0; it < 16; ++it) {
                int e = tid + it * 256;
                int nn = e >> 6, cc = e & 63;
                long idx = (long)(n0 + nn) * C2 + c0 + cc;
                sm.f.T[cc][nn] = b2f(h16[idx]) * sm.f.sv[c0 + cc] + b2f(idb16[idx]);
            }
            __syncthreads();
#pragma unroll
            for (int it = 0; it < 16; ++it) {
                int e = tid + it * 256;
                int cc = e >> 6, nn = e & 63;
                long idx = (long)(c0 + cc) * NN + n0 + nn;
                float v = sm.f.T[cc][nn];
                if (f32) ((float*)outp)[idx] = v;
                else     ((unsigned short*)outp)[idx] = f2b(v);
            }
            __syncthreads();
        }
    }
}

extern "C" void kernel_launch(void* const* d_in, const int* in_sizes, int n_in,
                              void* d_out, int out_size, void* d_ws, size_t ws_size,
                              hipStream_t stream) {
    float* ws = (float*)d_ws;
    float* cvt   = ws;                          // C_END
    float* means = ws + 35200;                  // 256 (64-aligned)
    int*   bar   = (int*)(means + 256);         // barrier counter
    float* als   = means + 320;                 // 204800
    float* ald   = als + 204800;
    unsigned short* wb16  = (unsigned short*)(ald + 204800);  // 262144
    unsigned short* xT16  = wb16 + B_WEND;                    // 25600*128
    unsigned short* xf16  = xT16 + NN * 128;                  // 25600*256 (residual)
    unsigned short* h16   = xf16 + NN * 256;                  // 25600*256 (h / y)
    unsigned short* idb16 = h16 + NN * 256;                   // 25600*256

    // zero means + bar in one memset (contiguous 320 floats incl. bar slot)
    hipMemsetAsync(means, 0, 320 * sizeof(float), stream);

    mega_kernel<<<GRID, 256, 0, stream>>>(
        (const unsigned short*)d_in[0],
        d_in[1], d_in[2], d_in[3], d_in[11],
        d_in[4], d_in[5], d_in[6], d_in[7], d_in[8], d_in[9], d_in[10],
        d_in[12], d_in[13], d_in[14], d_in[15],
        cvt, means, bar, als, ald,
        wb16, xT16, xf16, h16, idb16, d_out);
}

// Round 8
// 240.173 us; speedup vs baseline: 5.9978x; 3.7294x over previous
//
#include <hip/hip_runtime.h>

#define NN 25600      // nodes = 160*160
#define HH 160
#define WW 160
#define C2 256

// ---- bf16 weight pack offsets (ushorts) ----
#define B_WIN   0
#define B_WID   32768
#define B_WGAT  65536      // 2 layers x 65536
#define B_WOUT  196608
#define B_WEND  262144

// ---- small fp32 param offsets inside cvt (floats) ----
#define C_BNA   0          // 2x256 BN scale
#define C_BNB   512        // 2x256 BN shift (bias/mean folded)
#define C_ASRC  1024       // 2x256
#define C_ADST  1536       // 2x256
#define C_SEW1  2048       // 64x256
#define C_SEB1  18432      // 64
#define C_SEW2  18496      // 256x64
#define C_SEB2  34880      // 256
#define C_END   35136

typedef __attribute__((ext_vector_type(8))) short bfrag;   // 8 bf16 (4 VGPRs)
typedef __attribute__((ext_vector_type(4))) float ffrag;   // 4 fp32 acc

__device__ __forceinline__ float b2f(unsigned short u) {
    union { unsigned int ui; float f; } v; v.ui = ((unsigned int)u) << 16; return v.f;
}
__device__ __forceinline__ unsigned short f2b(float f) {
    union { float f; unsigned int u; } v; v.f = f;
    unsigned int u = v.u;
    unsigned int r = (u + 0x7FFFu + ((u >> 16) & 1u)) >> 16;
    return (unsigned short)r;
}
__device__ __forceinline__ float lo16f(unsigned int w) {
    union { unsigned int ui; float f; } v; v.ui = w << 16; return v.f;
}
__device__ __forceinline__ float hi16f(unsigned int w) {
    union { unsigned int ui; float f; } v; v.ui = w & 0xFFFF0000u; return v.f;
}
// Wave-uniform dtype probe on first 512 halfwords of x.
__device__ __forceinline__ bool probe_f32(const unsigned short* __restrict__ x) {
    int l = threadIdx.x & 63;
    bool wild = false;
#pragma unroll
    for (int i = 0; i < 8; ++i) {
        float v = b2f(x[l * 8 + i]);
        wild |= !(fabsf(v) < 1e6f);
    }
    return __any(wild);
}
__device__ __forceinline__ float ldf(const void* p, long i, bool f32) {
    return f32 ? ((const float*)p)[i] : b2f(((const unsigned short*)p)[i]);
}

// ---------------------------------------------------------------------------
// prep: pack weights bf16, fold BN, convert small params, zero means,
// AND transpose x -> bf16 [25600][128]. Grid = 400.
// ---------------------------------------------------------------------------
__global__ __launch_bounds__(256) void prep_kernel(
    const unsigned short* __restrict__ xp,
    const void* pwin, const void* pwid, const void* pwgat, const void* pwout,
    const void* pasrc, const void* padst, const void* pgbias,
    const void* pbng, const void* pbnb, const void* pbnm, const void* pbnv,
    const void* psew1, const void* pseb1, const void* psew2, const void* pseb2,
    unsigned short* __restrict__ wb, float* __restrict__ cvt,
    float* __restrict__ means, unsigned short* __restrict__ xT)
{
    __shared__ unsigned short T[64 * 136];
    const bool f32 = probe_f32(xp);
    const int tid = threadIdx.x;
    const int bid = blockIdx.x;
    const int gid = bid * 256 + tid;
    const int stride = gridDim.x * 256;

    if (bid == 0) means[tid] = 0.f;

    for (int i = gid; i < B_WEND; i += stride) {
        const void* s; int o;
        if      (i < B_WID)   { s = pwin;  o = i - B_WIN; }
        else if (i < B_WGAT)  { s = pwid;  o = i - B_WID; }
        else if (i < B_WOUT)  { s = pwgat; o = i - B_WGAT; }
        else                  { s = pwout; o = i - B_WOUT; }
        wb[i] = f32 ? f2b(((const float*)s)[o]) : ((const unsigned short*)s)[o];
    }
    for (int i = gid; i < 512; i += stride) {
        float sc = ldf(pbng, i, f32) * rsqrtf(ldf(pbnv, i, f32) + 1e-5f);
        cvt[C_BNA + i] = sc;
        cvt[C_BNB + i] = (ldf(pgbias, i, f32) - ldf(pbnm, i, f32)) * sc + ldf(pbnb, i, f32);
        cvt[C_ASRC + i] = ldf(pasrc, i, f32);
        cvt[C_ADST + i] = ldf(padst, i, f32);
    }
    for (int i = gid; i < 16384; i += stride) {
        cvt[C_SEW1 + i] = ldf(psew1, i, f32);
        cvt[C_SEW2 + i] = ldf(psew2, i, f32);
    }
    for (int i = gid; i < 64; i += stride)  cvt[C_SEB1 + i] = ldf(pseb1, i, f32);
    for (int i = gid; i < 256; i += stride) cvt[C_SEB2 + i] = ldf(pseb2, i, f32);

    // transpose slice: 64 nodes per block
    {
        const int n0 = bid * 64;
        const int nl = tid & 63;
#pragma unroll
        for (int i = 0; i < 32; ++i) {
            int c = i * 4 + (tid >> 6);
            long idx = (long)c * NN + n0 + nl;
            T[nl * 136 + c] = f32 ? f2b(((const float*)xp)[idx]) : xp[idx];
        }
        __syncthreads();
#pragma unroll
        for (int i = 0; i < 4; ++i) {
            int n = tid >> 2, c0 = (tid & 3) * 32 + i * 8;
            uint4 v = *(const uint4*)&T[n * 136 + c0];
            *(uint4*)(xT + (long)(n0 + n) * 128 + c0) = v;
        }
    }
}

// ---------------------------------------------------------------------------
// LDS epilogue helper layout: Cs[128][72] ushort (padded: 144 B row stride).
// ---------------------------------------------------------------------------
struct SmemG2 { unsigned short As[128*40], Bi[64*40], Bd[64*40]; }; // 20480 B
struct SmemG  { unsigned short As[128*40], Bs[64*40]; };            // 15360 B
struct SmemC  { unsigned short Cs[128*72]; };                       // 18432 B
union  SmemX2 { SmemG2 s; SmemC c; };
union  SmemNN { SmemG s; SmemC c; };

// ---------------------------------------------------------------------------
// MFMA GEMM (dual-B, K=128): xf16=A@Wi^T, idb16=A@Wd^T (both bf16).
// Coalesced C stores via LDS staging.
// ---------------------------------------------------------------------------
__global__ __launch_bounds__(256) void mfma_gemm_x2_kernel(
    const unsigned short* __restrict__ A16,
    const unsigned short* __restrict__ Wi16,
    const unsigned short* __restrict__ Wd16,
    unsigned short* __restrict__ xf16,
    unsigned short* __restrict__ idb16)
{
    __shared__ SmemX2 sm;
    const int tid = threadIdx.x;
    const int m0 = blockIdx.x * 128, o0 = blockIdx.y * 64;
    const int lane = tid & 63, wv = tid >> 6;
    const int wm = wv >> 1, wn = wv & 1;
    const int lr = lane & 15, quad = lane >> 4;

    ffrag ai[4][2], ad[4][2];
#pragma unroll
    for (int mt = 0; mt < 4; ++mt)
#pragma unroll
        for (int nt = 0; nt < 2; ++nt) { ai[mt][nt] = (ffrag){0,0,0,0}; ad[mt][nt] = (ffrag){0,0,0,0}; }

    for (int k0 = 0; k0 < 128; k0 += 32) {
#pragma unroll
        for (int c = tid; c < 512; c += 256) {
            int row = c >> 2, q = c & 3;
            uint4 v = *(const uint4*)(A16 + (long)(m0 + row) * 128 + k0 + q * 8);
            *(uint4*)&sm.s.As[row * 40 + q * 8] = v;
        }
        {
            int row = tid >> 2, q = tid & 3;
            uint4 vi = *(const uint4*)(Wi16 + (long)(o0 + row) * 128 + k0 + q * 8);
            uint4 vd = *(const uint4*)(Wd16 + (long)(o0 + row) * 128 + k0 + q * 8);
            *(uint4*)&sm.s.Bi[row * 40 + q * 8] = vi;
            *(uint4*)&sm.s.Bd[row * 40 + q * 8] = vd;
        }
        __syncthreads();
        bfrag a[4], bi[2], bd[2];
#pragma unroll
        for (int mt = 0; mt < 4; ++mt)
            a[mt] = *(const bfrag*)&sm.s.As[(wm * 64 + mt * 16 + lr) * 40 + quad * 8];
#pragma unroll
        for (int nt = 0; nt < 2; ++nt) {
            bi[nt] = *(const bfrag*)&sm.s.Bi[(wn * 32 + nt * 16 + lr) * 40 + quad * 8];
            bd[nt] = *(const bfrag*)&sm.s.Bd[(wn * 32 + nt * 16 + lr) * 40 + quad * 8];
        }
#pragma unroll
        for (int mt = 0; mt < 4; ++mt)
#pragma unroll
            for (int nt = 0; nt < 2; ++nt) {
                ai[mt][nt] = __builtin_amdgcn_mfma_f32_16x16x32_bf16(a[mt], bi[nt], ai[mt][nt], 0, 0, 0);
                ad[mt][nt] = __builtin_amdgcn_mfma_f32_16x16x32_bf16(a[mt], bd[nt], ad[mt][nt], 0, 0, 0);
            }
        __syncthreads();
    }
    // epilogue 1: xf16 via LDS -> coalesced uint4 stores
#pragma unroll
    for (int mt = 0; mt < 4; ++mt)
#pragma unroll
        for (int nt = 0; nt < 2; ++nt)
#pragma unroll
            for (int r = 0; r < 4; ++r)
                sm.c.Cs[(wm * 64 + mt * 16 + quad * 4 + r) * 72 + wn * 32 + nt * 16 + lr] = f2b(ai[mt][nt][r]);
    __syncthreads();
#pragma unroll
    for (int it = 0; it < 4; ++it) {
        int e = it * 256 + tid;
        int row = e >> 3, c8 = (e & 7) * 8;
        *(uint4*)(xf16 + (long)(m0 + row) * C2 + o0 + c8) = *(const uint4*)&sm.c.Cs[row * 72 + c8];
    }
    __syncthreads();
    // epilogue 2: idb16
#pragma unroll
    for (int mt = 0; mt < 4; ++mt)
#pragma unroll
        for (int nt = 0; nt < 2; ++nt)
#pragma unroll
            for (int r = 0; r < 4; ++r)
                sm.c.Cs[(wm * 64 + mt * 16 + quad * 4 + r) * 72 + wn * 32 + nt * 16 + lr] = f2b(ad[mt][nt][r]);
    __syncthreads();
#pragma unroll
    for (int it = 0; it < 4; ++it) {
        int e = it * 256 + tid;
        int row = e >> 3, c8 = (e & 7) * 8;
        *(uint4*)(idb16 + (long)(m0 + row) * C2 + o0 + c8) = *(const uint4*)&sm.c.Cs[row * 72 + c8];
    }
}

// ---------------------------------------------------------------------------
// MFMA GEMM (K=256): C16 = A@W^T (bf16), coalesced stores via LDS.
// mode 1: attn epilogue (al_s/al_d). mode 2: colsum -> means atomics.
// ---------------------------------------------------------------------------
__global__ __launch_bounds__(256) void mfma_gemm_nn_kernel(
    const unsigned short* __restrict__ A16,
    const unsigned short* __restrict__ W16,
    unsigned short* __restrict__ C16,
    const float* __restrict__ asrc, const float* __restrict__ adst,
    float* __restrict__ al_s, float* __restrict__ al_d,
    float* __restrict__ means,
    int mode)
{
    __shared__ SmemNN sm;
    const int tid = threadIdx.x;
    const int m0 = blockIdx.x * 128, o0 = blockIdx.y * 64;
    const int lane = tid & 63, wv = tid >> 6;
    const int wm = wv >> 1, wn = wv & 1;
    const int lr = lane & 15, quad = lane >> 4;

    ffrag acc[4][2];
#pragma unroll
    for (int mt = 0; mt < 4; ++mt)
#pragma unroll
        for (int nt = 0; nt < 2; ++nt) acc[mt][nt] = (ffrag){0,0,0,0};

    for (int k0 = 0; k0 < 256; k0 += 32) {
#pragma unroll
        for (int c = tid; c < 512; c += 256) {
            int row = c >> 2, q = c & 3;
            uint4 v = *(const uint4*)(A16 + (long)(m0 + row) * 256 + k0 + q * 8);
            *(uint4*)&sm.s.As[row * 40 + q * 8] = v;
        }
        {
            int row = tid >> 2, q = tid & 3;
            uint4 v = *(const uint4*)(W16 + (long)(o0 + row) * 256 + k0 + q * 8);
            *(uint4*)&sm.s.Bs[row * 40 + q * 8] = v;
        }
        __syncthreads();
        bfrag a[4], b[2];
#pragma unroll
        for (int mt = 0; mt < 4; ++mt)
            a[mt] = *(const bfrag*)&sm.s.As[(wm * 64 + mt * 16 + lr) * 40 + quad * 8];
#pragma unroll
        for (int nt = 0; nt < 2; ++nt)
            b[nt] = *(const bfrag*)&sm.s.Bs[(wn * 32 + nt * 16 + lr) * 40 + quad * 8];
#pragma unroll
        for (int mt = 0; mt < 4; ++mt)
#pragma unroll
            for (int nt = 0; nt < 2; ++nt)
                acc[mt][nt] = __builtin_amdgcn_mfma_f32_16x16x32_bf16(a[mt], b[nt], acc[mt][nt], 0, 0, 0);
        __syncthreads();
    }
    // C via LDS -> coalesced stores
#pragma unroll
    for (int mt = 0; mt < 4; ++mt)
#pragma unroll
        for (int nt = 0; nt < 2; ++nt)
#pragma unroll
            for (int r = 0; r < 4; ++r)
                sm.c.Cs[(wm * 64 + mt * 16 + quad * 4 + r) * 72 + wn * 32 + nt * 16 + lr] = f2b(acc[mt][nt][r]);
    __syncthreads();
#pragma unroll
    for (int it = 0; it < 4; ++it) {
        int e = it * 256 + tid;
        int row = e >> 3, c8 = (e & 7) * 8;
        *(uint4*)(C16 + (long)(m0 + row) * C2 + o0 + c8) = *(const uint4*)&sm.c.Cs[row * 72 + c8];
    }
    if (mode == 1) {
        const int head = blockIdx.y * 2 + wn;
        const float as0 = asrc[head * 32 + lr], as1 = asrc[head * 32 + 16 + lr];
        const float ad0 = adst[head * 32 + lr], ad1 = adst[head * 32 + 16 + lr];
#pragma unroll
        for (int mt = 0; mt < 4; ++mt)
#pragma unroll
            for (int r = 0; r < 4; ++r) {
                float ps = acc[mt][0][r] * as0 + acc[mt][1][r] * as1;
                float pd = acc[mt][0][r] * ad0 + acc[mt][1][r] * ad1;
#pragma unroll
                for (int sh = 1; sh < 16; sh <<= 1) {
                    ps += __shfl_xor(ps, sh);
                    pd += __shfl_xor(pd, sh);
                }
                if (lr == 0) {
                    int m = m0 + wm * 64 + mt * 16 + quad * 4 + r;
                    al_s[m * 8 + head] = ps;
                    al_d[m * 8 + head] = pd;
                }
            }
    } else if (mode == 2) {
#pragma unroll
        for (int nt = 0; nt < 2; ++nt) {
            float p = 0.f;
#pragma unroll
            for (int mt = 0; mt < 4; ++mt)
#pragma unroll
                for (int r = 0; r < 4; ++r) p += acc[mt][nt][r];
            p += __shfl_xor(p, 16);
            p += __shfl_xor(p, 32);
            if (quad == 0) atomicAdd(&means[o0 + wn * 32 + nt * 16 + lr], p);
        }
    }
}

// ---------------------------------------------------------------------------
// Aggregation: 8 nodes/block, 32 thr/node, 8 bf16 channels/thread.
// ---------------------------------------------------------------------------
__global__ __launch_bounds__(256) void aggregate_kernel(
    const unsigned short* __restrict__ h16,
    const float* __restrict__ al_s,
    const float* __restrict__ al_d,
    const float* __restrict__ bnA,
    const float* __restrict__ bnB,
    unsigned short* __restrict__ xf16)
{
    const int SI[11] = { 1, 1, 1, 0, 0, -1, -1, -1, -2,  0, 0};
    const int SJ[11] = { 1, 0,-1, 1,-1,  1,  0, -1,  0, -2, 0};
    __shared__ float es[8][11][8];
    __shared__ float alpha[8][11][8];

    const int t = threadIdx.x;
    const int ln = t >> 5;
    const int l = t & 31;
    const int n = blockIdx.x * 8 + ln;
    const int i = n / WW, j = n % WW;

    for (int idx = t; idx < 704; idx += 256) {
        int lln = idx / 88, rem = idx - lln * 88;
        int k = rem >> 3, hh = rem & 7;
        int nn2 = blockIdx.x * 8 + lln;
        int ii = nn2 / WW, jj = nn2 - ii * WW;
        int si = ii + SI[k], sj = jj + SJ[k];
        bool okk = (si >= 0) & (si < HH) & (sj >= 0) & (sj < WW);
        es[lln][k][hh] = okk ? al_s[(si * WW + sj) * 8 + hh] : -1e30f;
    }
    __syncthreads();

    if (l < 8) {
        const int hd = l;
        const float ald = al_d[n * 8 + hd];
        float e[11];
        float mx = -1e30f;
#pragma unroll
        for (int k = 0; k < 11; ++k) {
            float v = es[ln][k][hd] + ald;
            v = v > 0.f ? v : 0.2f * v;
            e[k] = v;
            mx = fmaxf(mx, v);
        }
        float denom = 0.f;
#pragma unroll
        for (int k = 0; k < 11; ++k) {
            float p = __expf(e[k] - mx);
            e[k] = p;
            denom += p;
        }
        const float inv = 1.f / (denom + 1e-16f);
#pragma unroll
        for (int k = 0; k < 11; ++k) alpha[ln][k][hd] = e[k] * inv;
    }
    __syncthreads();

    const int c8 = l * 8;
    const int hd = l >> 2;
    int srcn[11];
#pragma unroll
    for (int k = 0; k < 11; ++k) {
        int si = i + SI[k], sj = j + SJ[k];
        bool ok = (si >= 0) & (si < HH) & (sj >= 0) & (sj < WW);
        srcn[k] = ok ? si * WW + sj : n;
    }
    float a0=0.f,a1=0.f,a2=0.f,a3=0.f,a4=0.f,a5=0.f,a6=0.f,a7=0.f;
#pragma unroll
    for (int k = 0; k < 11; ++k) {
        float al = alpha[ln][k][hd];
        uint4 hv = *(const uint4*)(h16 + (long)srcn[k] * C2 + c8);
        a0 += al * lo16f(hv.x); a1 += al * hi16f(hv.x);
        a2 += al * lo16f(hv.y); a3 += al * hi16f(hv.y);
        a4 += al * lo16f(hv.z); a5 += al * hi16f(hv.z);
        a6 += al * lo16f(hv.w); a7 += al * hi16f(hv.w);
    }
    float acc8[8] = {a0,a1,a2,a3,a4,a5,a6,a7};
    uint4 rv = *(const uint4*)(xf16 + (long)n * C2 + c8);
    float res[8] = {lo16f(rv.x),hi16f(rv.x),lo16f(rv.y),hi16f(rv.y),
                    lo16f(rv.z),hi16f(rv.z),lo16f(rv.w),hi16f(rv.w)};
    float out[8];
#pragma unroll
    for (int q = 0; q < 8; ++q) {
        int c = c8 + q;
        float g = acc8[q] * bnA[c] + bnB[c];
        out[q] = fmaxf(g, 0.f) + res[q];
    }
    ushort4 o16a, o16b;
    o16a.x = f2b(out[0]); o16a.y = f2b(out[1]); o16a.z = f2b(out[2]); o16a.w = f2b(out[3]);
    o16b.x = f2b(out[4]); o16b.y = f2b(out[5]); o16b.z = f2b(out[6]); o16b.w = f2b(out[7]);
    *(ushort4*)(xf16 + (long)n * C2 + c8)     = o16a;
    *(ushort4*)(xf16 + (long)n * C2 + c8 + 4) = o16b;
}

// ---------------------------------------------------------------------------
// Final: SE vector from means (redundant per block), then
// out[c][n] = y[n][c]*s[c] + id[n][c] (transposed store; dtype by probe).
// ---------------------------------------------------------------------------
__global__ __launch_bounds__(256) void final_kernel(
    const unsigned short* __restrict__ x_probe,
    const unsigned short* __restrict__ y16,
    const unsigned short* __restrict__ idb16,
    const float* __restrict__ means,
    const float* __restrict__ cvt,
    void* __restrict__ outp)
{
    __shared__ float T[64][65];
    __shared__ float mv[256];
    __shared__ float hv[64];
    __shared__ float sv[64];
    const bool f32o = probe_f32(x_probe);
    const int t = threadIdx.x;
    const int n0 = blockIdx.x * 64, c0 = blockIdx.y * 64;

    mv[t] = means[t] * (1.0f / 25600.0f);
    __syncthreads();
    if (t < 64) {
        const float* w1 = cvt + C_SEW1 + t * 256;
        float s = cvt[C_SEB1 + t];
        for (int cc = 0; cc < 256; cc += 4) {
            float4 wv = *(const float4*)(w1 + cc);
            s += wv.x * mv[cc] + wv.y * mv[cc+1] + wv.z * mv[cc+2] + wv.w * mv[cc+3];
        }
        hv[t] = fmaxf(s, 0.f);
    }
    __syncthreads();
    if (t < 64) {
        const int c = c0 + t;
        const float* w2 = cvt + C_SEW2 + c * 64;
        float s = cvt[C_SEB2 + c];
        for (int k = 0; k < 64; k += 4) {
            float4 wv = *(const float4*)(w2 + k);
            s += wv.x * hv[k] + wv.y * hv[k+1] + wv.z * hv[k+2] + wv.w * hv[k+3];
        }
        sv[t] = 1.0f / (1.0f + __expf(-s));
    }
    __syncthreads();
#pragma unroll
    for (int it = 0; it < 16; ++it) {
        int e = t + it * 256;
        int nn = e >> 6, cc = e & 63;
        long idx = (long)(n0 + nn) * C2 + c0 + cc;
        T[cc][nn] = b2f(y16[idx]) * sv[cc] + b2f(idb16[idx]);
    }
    __syncthreads();
#pragma unroll
    for (int it = 0; it < 16; ++it) {
        int e = t + it * 256;
        int cc = e >> 6, nn = e & 63;
        long idx = (long)(c0 + cc) * NN + n0 + nn;
        float v = T[cc][nn];
        if (f32o) ((float*)outp)[idx] = v;
        else      ((unsigned short*)outp)[idx] = f2b(v);
    }
}

extern "C" void kernel_launch(void* const* d_in, const int* in_sizes, int n_in,
                              void* d_out, int out_size, void* d_ws, size_t ws_size,
                              hipStream_t stream) {
    float* ws = (float*)d_ws;
    float* cvt   = ws;                          // C_END small fp32 params
    float* means = ws + 35200;                  // 256 (64-aligned)
    float* als   = means + 256;                 // 204800
    float* ald   = als + 204800;
    unsigned short* wb16  = (unsigned short*)(ald + 204800);  // 262144
    unsigned short* xT16  = wb16 + B_WEND;                    // 25600*128
    unsigned short* xf16  = xT16 + NN * 128;                  // 25600*256 (residual)
    unsigned short* h16   = xf16 + NN * 256;                  // 25600*256 (h / y)
    unsigned short* idb16 = h16 + NN * 256;                   // 25600*256

    const unsigned short* xp = (const unsigned short*)d_in[0];

    dim3 b256(256);
    dim3 gmfma(NN / 128, C2 / 64);     // 200 x 4
    dim3 gfin(NN / 64, C2 / 64);       // 400 x 4

    prep_kernel<<<400, b256, 0, stream>>>(
        xp, d_in[2], d_in[1], d_in[3], d_in[11],
        d_in[4], d_in[5], d_in[6], d_in[7], d_in[8], d_in[9], d_in[10],
        d_in[12], d_in[13], d_in[14], d_in[15],
        wb16, cvt, means, xT16);

    mfma_gemm_x2_kernel<<<gmfma, b256, 0, stream>>>(
        xT16, wb16 + B_WIN, wb16 + B_WID, xf16, idb16);

    for (int l = 0; l < 2; ++l) {
        mfma_gemm_nn_kernel<<<gmfma, b256, 0, stream>>>(
            xf16, wb16 + B_WGAT + l * 65536, h16,
            cvt + C_ASRC + l * 256, cvt + C_ADST + l * 256, als, ald, nullptr, 1);
        aggregate_kernel<<<NN / 8, b256, 0, stream>>>(h16, als, ald,
            cvt + C_BNA + l * 256, cvt + C_BNB + l * 256, xf16);
    }

    mfma_gemm_nn_kernel<<<gmfma, b256, 0, stream>>>(
        xf16, wb16 + B_WOUT, h16, nullptr, nullptr, nullptr, nullptr, means, 2);
    final_kernel<<<gfin, b256, 0, stream>>>(xp, h16, idb16, means, cvt, d_out);
}